// Round 13
// baseline (1400.241 us; speedup 1.0000x reference)
//
#include <hip/hip_runtime.h>

#define BATCH  131072
#define NSTEPS 100

typedef _Float16 half8  __attribute__((ext_vector_type(8)));
typedef _Float16 h2     __attribute__((ext_vector_type(2)));
typedef float    f32x4  __attribute__((ext_vector_type(4)));
typedef float    f32x2  __attribute__((ext_vector_type(2)));
typedef unsigned u32x4  __attribute__((ext_vector_type(4)));

__device__ __forceinline__ unsigned pkh2(float a, float b) {
    return __builtin_bit_cast(unsigned, __builtin_amdgcn_cvt_pkrtz(a, b));
}
__device__ __forceinline__ float loh(unsigned u) {
    h2 h = __builtin_bit_cast(h2, u); return (float)h[0];
}
__device__ __forceinline__ float hih(unsigned u) {
    h2 h = __builtin_bit_cast(h2, u); return (float)h[1];
}

// True packed-f16 ops via inline asm (VOP3P). R12 proved clang promotes
// _Float16x2 arithmetic to f32 (3.6 inst/op); these are 1 inst each.
__device__ __forceinline__ unsigned pkmul(unsigned a, unsigned b) {
    unsigned d;
    asm("v_pk_mul_f16 %0, %1, %2" : "=v"(d) : "v"(a), "v"(b));
    return d;
}
__device__ __forceinline__ unsigned pkadd(unsigned a, unsigned b) {
    unsigned d;
    asm("v_pk_add_f16 %0, %1, %2" : "=v"(d) : "v"(a), "v"(b));
    return d;
}
__device__ __forceinline__ unsigned pkfma(unsigned a, unsigned b, unsigned c) {
    unsigned d;
    asm("v_pk_fma_f16 %0, %1, %2, %3" : "=v"(d) : "v"(a), "v"(b), "v"(c));
    return d;
}

// ---------------------------------------------------------------------------
// Packed-f16 sincos pair (R12 math, now forced to v_pk_* via asm):
// f32 range-reduce to v in [-0.5,0.5] turns (exact), one cvt_pkrtz pack,
// sin(pi v) deg-7 / cos(pi v) deg-8 Taylor-Horner in pk-f16, double-angle.
// 20 inst per pair = 10/sincos (OCML __sincosf ~17/sincos). Outputs are the
// exact u32 B-frag words. Numerics HW-verified by R12 (absmax 0.0).
// ---------------------------------------------------------------------------
__device__ __forceinline__ void pksincos2(float z0, float z1,
                                          unsigned kC1, unsigned kC3,
                                          unsigned kC5, unsigned kC7,
                                          unsigned kD2, unsigned kD4,
                                          unsigned kD6, unsigned kD8,
                                          unsigned kONE, unsigned kMTWO,
                                          unsigned& so, unsigned& co) {
    const float I2PI = 0.15915494309189535f;
    float m0 = z0 * I2PI, m1 = z1 * I2PI;
    float v0 = m0 - __builtin_rintf(m0);
    float v1 = m1 - __builtin_rintf(m1);
    unsigned v = pkh2(v0, v1);
    unsigned w = pkmul(v, v);
    unsigned sh = pkmul(v, pkfma(w, pkfma(w, pkfma(w, kC7, kC5), kC3), kC1));
    unsigned ch = pkfma(w, pkfma(w, pkfma(w, pkfma(w, kD8, kD6), kD4), kD2), kONE);
    unsigned tt = pkmul(sh, ch);
    so = pkadd(tt, tt);                    // sin(2 pi v) = sin(z)
    unsigned uu = pkmul(sh, sh);
    co = pkfma(uu, kMTWO, kONE);           // cos(2 pi v) = 1 - 2 sh^2
}

#define PKARGS kC1, kC3, kC5, kC7, kD2, kD4, kD6, kD8, kONE, kMTWO

// ---------------------------------------------------------------------------
// R9 structure: weights staged once in LDS; A-frags persistent in registers;
// activations pure-register; barrier-free loop; __launch_bounds__(256,2).
// This round: sincos + all downstream f16 packing via asm-pk f16 pipeline.
// Wave owns 16 samples; lane (c=l&15, g=l>>4). B-frag (kt,qq,r) holds neuron
// n = 32kt+16qq+4g+r; C layout row = 16mt+4g+r makes lane g's C-quads exactly
// its next-layer B-frags (mapping HW-verified R5-R12).
// ---------------------------------------------------------------------------
extern "C" __global__ void __launch_bounds__(256, 2)
fbsnn_kernel(const float* __restrict__ W0, const float* __restrict__ b0,
             const float* __restrict__ W1, const float* __restrict__ b1,
             const float* __restrict__ W2, const float* __restrict__ b2,
             const float* __restrict__ W3, const float* __restrict__ b3,
             const float* __restrict__ W4, const float* __restrict__ b4,
             const float* __restrict__ y0p, const float* __restrict__ dW,
             float* __restrict__ slots)
{
    __shared__ unsigned ldsA[6144];    // A-frags, u32-packed f16 pairs (24.5 KB)
    __shared__ float    ldsWA[64];     // L0 t-weights, pairs per (g,qi,h)
    __shared__ float    ldsWB[64];     // L0 y-weights
    __shared__ float    ldsB0[64];     // L0 bias
    __shared__ float    ldsBias[192];  // [li][mt][g][r]
    __shared__ float    ldsW4[64];     // [mt][g][r]

    const int tid = threadIdx.x;
    const int l   = tid & 63;
    const int wu  = tid >> 6;
    const int c   = l & 15;
    const int g   = l >> 4;
    const int sample = blockIdx.x * 64 + wu * 16 + c;

    const float DT = 0.01f, SQDT = 0.1f;

    // packed poly coefficients (hoisted, loop-invariant)
    const unsigned kC1  = pkh2( 3.14159265f,  3.14159265f);
    const unsigned kC3  = pkh2(-5.16771278f, -5.16771278f);
    const unsigned kC5  = pkh2( 2.55016404f,  2.55016404f);
    const unsigned kC7  = pkh2(-0.59926453f, -0.59926453f);
    const unsigned kD2  = pkh2(-4.93480220f, -4.93480220f);
    const unsigned kD4  = pkh2( 4.05871213f,  4.05871213f);
    const unsigned kD6  = pkh2(-1.33526277f, -1.33526277f);
    const unsigned kD8  = pkh2( 0.23533063f,  0.23533063f);
    const unsigned kONE = pkh2( 1.0f,  1.0f);
    const unsigned kMTWO= pkh2(-2.0f, -2.0f);

    // ================= prep: stage weights into LDS =================
    {
        for (int idx = tid; idx < 6144; idx += 256) {
            int w   = idx & 3;
            int lam = (idx >> 2) & 63;
            int f   = (idx >> 8) & 7;
            int li  = idx >> 11;
            const float* Wsl = (li == 0) ? W1 : (li == 1) ? W2 : W3;
            int cc = lam & 15, gg = lam >> 4;
            int mt = f >> 1, kt = f & 1;
            int m = 16 * mt + cc;
            int k = 32 * kt + 16 * (w >> 1) + 4 * gg + ((2 * w) & 3);
            const float* Wp = Wsl + m * 64 + k;
            ldsA[(8 * li + f) * 256 + lam * 4 + w] = pkh2(Wp[0], Wp[1]);
        }
        if (tid < 32) {
            int gg = tid >> 3, qi = (tid >> 1) & 3, h = tid & 1;
            int n0 = 32 * (qi >> 1) + 16 * (qi & 1) + 4 * gg + 2 * h;
            ldsWA[2 * tid]     = W0[2 * n0];
            ldsWA[2 * tid + 1] = W0[2 * n0 + 2];
            ldsWB[2 * tid]     = W0[2 * n0 + 1];
            ldsWB[2 * tid + 1] = W0[2 * n0 + 3];
            ldsB0[2 * tid]     = b0[n0];
            ldsB0[2 * tid + 1] = b0[n0 + 1];
        }
        if (tid < 192) {
            int li = tid >> 6, mt = (tid >> 4) & 3, gg = (tid >> 2) & 3, r = tid & 3;
            ldsBias[tid] = ((li == 0) ? b1 : (li == 1) ? b2 : b3)[16 * mt + 4 * gg + r];
        }
        if (tid < 64) {
            int mt = tid >> 4, gg = (tid >> 2) & 3, r = tid & 3;
            ldsW4[tid] = W4[16 * mt + 4 * gg + r];
        }
    }
    __syncthreads();   // only barrier; LDS is read-only below

    // ---- persistent A-fragments: load once, keep in registers (96 regs) ----
    half8 AF[3][4][2];
    #pragma unroll
    for (int li = 0; li < 3; ++li)
        #pragma unroll
        for (int mt = 0; mt < 4; ++mt)
            #pragma unroll
            for (int kt = 0; kt < 2; ++kt)
                AF[li][mt][kt] =
                    *(const half8*)&ldsA[(8 * li + 2 * mt + kt) * 256 + l * 4];

    // ---- W4 as packed u32 pairs ----
    unsigned W4p[4][2];
    #pragma unroll
    for (int mt = 0; mt < 4; ++mt) {
        f32x4 wv = *(const f32x4*)&ldsW4[(mt * 4 + g) * 4];
        W4p[mt][0] = pkh2(wv[0], wv[1]);
        W4p[mt][1] = pkh2(wv[2], wv[3]);
    }

    const float b4v = b4[0];
    float y = y0p[0];
    float t = 0.0f;
    float Y0 = 0.f, dY0 = 0.f, q0 = 0.f, Z0 = 0.f, dws = 0.f, loss = 0.f;

    #pragma unroll 1
    for (int s = 0; s <= NSTEPS; ++s) {
        float dwv = 0.0f;
        if (s < NSTEPS) dwv = dW[s * BATCH + sample];   // prefetch early

        // ============ layer 0: build B-frags in registers ============
        half8 BX[2], BV[2];
        #pragma unroll
        for (int kt = 0; kt < 2; ++kt) {
            u32x4 ux, uv;
            #pragma unroll
            for (int qq = 0; qq < 2; ++qq) {
                int qi = 2 * kt + qq;
                #pragma unroll
                for (int h = 0; h < 2; ++h) {
                    int o = g * 8 + qi * 2 + h;
                    f32x2 wa = *(const f32x2*)&ldsWA[2 * o];
                    f32x2 wb = *(const f32x2*)&ldsWB[2 * o];
                    f32x2 bb = *(const f32x2*)&ldsB0[2 * o];
                    float z0 = fmaf(wa[0], t, fmaf(wb[0], y, bb[0]));
                    float z1 = fmaf(wa[1], t, fmaf(wb[1], y, bb[1]));
                    unsigned so, co;
                    pksincos2(z0, z1, PKARGS, so, co);
                    unsigned wbp = pkh2(wb[0], wb[1]);
                    ux[2 * qq + h] = so;
                    uv[2 * qq + h] = pkmul(co, wbp);
                }
            }
            BX[kt] = __builtin_bit_cast(half8, ux);
            BV[kt] = __builtin_bit_cast(half8, uv);
        }

        // ============ hidden layers 1..3 ============
        float Y1 = 0.f, dY1 = 0.f;
        #pragma unroll
        for (int li = 0; li < 3; ++li) {
            f32x4 ax[4], av[4];
            #pragma unroll
            for (int mt = 0; mt < 4; ++mt) {
                f32x4 ci = *(const f32x4*)&ldsBias[((li * 4 + mt) * 4 + g) * 4];
                f32x4 a = __builtin_amdgcn_mfma_f32_16x16x32_f16(AF[li][mt][0], BX[0], ci, 0, 0, 0);
                a = __builtin_amdgcn_mfma_f32_16x16x32_f16(AF[li][mt][1], BX[1], a, 0, 0, 0);
                ax[mt] = a;
                f32x4 v = {0.f, 0.f, 0.f, 0.f};
                v = __builtin_amdgcn_mfma_f32_16x16x32_f16(AF[li][mt][0], BV[0], v, 0, 0, 0);
                v = __builtin_amdgcn_mfma_f32_16x16x32_f16(AF[li][mt][1], BV[1], v, 0, 0, 0);
                av[mt] = v;
            }
            if (li < 2) {
                u32x4 nx[2], nv[2];
                #pragma unroll
                for (int mt = 0; mt < 4; ++mt) {
                    unsigned so0, co0, so1, co1;
                    pksincos2(ax[mt][0], ax[mt][1], PKARGS, so0, co0);
                    pksincos2(ax[mt][2], ax[mt][3], PKARGS, so1, co1);
                    unsigned avp0 = pkh2(av[mt][0], av[mt][1]);
                    unsigned avp1 = pkh2(av[mt][2], av[mt][3]);
                    nx[mt >> 1][2 * (mt & 1) + 0] = so0;
                    nx[mt >> 1][2 * (mt & 1) + 1] = so1;
                    nv[mt >> 1][2 * (mt & 1) + 0] = pkmul(co0, avp0);
                    nv[mt >> 1][2 * (mt & 1) + 1] = pkmul(co1, avp1);
                }
                BX[0] = __builtin_bit_cast(half8, nx[0]);
                BX[1] = __builtin_bit_cast(half8, nx[1]);
                BV[0] = __builtin_bit_cast(half8, nv[0]);
                BV[1] = __builtin_bit_cast(half8, nv[1]);
            } else {
                // L3 epilogue: fold W4 dot in packed f16, then f32 reduce
                unsigned sxp = 0u, svp = 0u;   // packed (+0.0h, +0.0h)
                #pragma unroll
                for (int mt = 0; mt < 4; ++mt) {
                    unsigned so0, co0, so1, co1;
                    pksincos2(ax[mt][0], ax[mt][1], PKARGS, so0, co0);
                    pksincos2(ax[mt][2], ax[mt][3], PKARGS, so1, co1);
                    unsigned avp0 = pkh2(av[mt][0], av[mt][1]);
                    unsigned avp1 = pkh2(av[mt][2], av[mt][3]);
                    sxp = pkfma(W4p[mt][0], so0, sxp);
                    sxp = pkfma(W4p[mt][1], so1, sxp);
                    svp = pkfma(W4p[mt][0], pkmul(co0, avp0), svp);
                    svp = pkfma(W4p[mt][1], pkmul(co1, avp1), svp);
                }
                float sx = loh(sxp) + hih(sxp);
                float sv = loh(svp) + hih(svp);
                sx += __shfl_xor(sx, 16); sx += __shfl_xor(sx, 32);
                sv += __shfl_xor(sv, 16); sv += __shfl_xor(sv, 32);
                Y1  = sx + b4v;
                dY1 = sv;
            }
        }

        // ============ trajectory / loss ============
        if (s > 0) {
            float Yt = Y0 - q0 * q0 * DT + Z0 * dws;
            float d  = Y1 - Yt;
            loss += d * d;
        }
        Y0 = Y1; dY0 = dY1;
        if (s < NSTEPS) {
            Z0  = 0.5f * dY0;
            q0  = -dY0;                 // exact (power-of-2 constants)
            dws = dwv * SQDT;
            y   = y + q0 * DT + 0.5f * dws;
            t   = t + DT;
        }
    }

    // terminal: (YN - yN^2)^2 + (dYN - 2*yN)^2
    float d1 = Y0 - y * y;
    float d2 = dY0 - 2.0f * y;
    loss += d1 * d1 + d2 * d2;

    // 4 g-lanes share a sample -> mask, then wave butterfly
    float lv = (g == 0) ? loss : 0.0f;
    #pragma unroll
    for (int off = 1; off < 64; off <<= 1)
        lv += __shfl_xor(lv, off);
    if (l == 0)
        atomicAdd(&slots[(blockIdx.x * 4 + wu) & 255], lv);
}

extern "C" __global__ void finish_kernel(const float* __restrict__ slots,
                                         float* __restrict__ out) {
    int l = threadIdx.x;   // 64 threads
    float v = slots[l] + slots[64 + l] + slots[128 + l] + slots[192 + l];
    #pragma unroll
    for (int off = 1; off < 64; off <<= 1)
        v += __shfl_xor(v, off);
    if (l == 0) out[0] = v * (1.0f / (float)BATCH);
}

extern "C" void kernel_launch(void* const* d_in, const int* in_sizes, int n_in,
                              void* d_out, int out_size, void* d_ws, size_t ws_size,
                              hipStream_t stream) {
    const float* W0  = (const float*)d_in[0];
    const float* b0  = (const float*)d_in[1];
    const float* W1  = (const float*)d_in[2];
    const float* b1  = (const float*)d_in[3];
    const float* W2  = (const float*)d_in[4];
    const float* b2  = (const float*)d_in[5];
    const float* W3  = (const float*)d_in[6];
    const float* b3  = (const float*)d_in[7];
    const float* W4  = (const float*)d_in[8];
    const float* b4  = (const float*)d_in[9];
    const float* y0p = (const float*)d_in[10];
    const float* dW  = (const float*)d_in[11];
    float* slots = (float*)d_ws;

    (void)hipMemsetAsync(d_ws, 0, 256 * sizeof(float), stream);

    dim3 grid(BATCH / 64);   // 2048 blocks x 4 independent waves (16 samples)
    dim3 block(256);
    fbsnn_kernel<<<grid, block, 0, stream>>>(W0, b0, W1, b1, W2, b2, W3, b3,
                                             W4, b4, y0p, dW, slots);
    finish_kernel<<<1, 64, 0, stream>>>(slots, (float*)d_out);
}

// Round 14
// 1000.481 us; speedup vs baseline: 1.3996x; 1.3996x over previous
//
#include <hip/hip_runtime.h>

#define BATCH  131072
#define NSTEPS 100

typedef _Float16 half8  __attribute__((ext_vector_type(8)));
typedef _Float16 h2     __attribute__((ext_vector_type(2)));
typedef float    f32x4  __attribute__((ext_vector_type(4)));
typedef float    f32x2  __attribute__((ext_vector_type(2)));
typedef unsigned u32x4  __attribute__((ext_vector_type(4)));

__device__ __forceinline__ unsigned pkh2(float a, float b) {
    return __builtin_bit_cast(unsigned, __builtin_amdgcn_cvt_pkrtz(a, b));
}

// Trans-pipe sincos (R10-proven): exact revolutions identity,
// sin(z) = sin(2pi * fract(z/2pi)). 2 full-rate + 2 trans ops.
__device__ __forceinline__ void tsincos(float z, float& s, float& c) {
    float u = __builtin_amdgcn_fractf(z * 0.15915494309189535f);
    s = __builtin_amdgcn_sinf(u);
    c = __builtin_amdgcn_cosf(u);
}

// ---------------------------------------------------------------------------
// R9 structure (best verified: 942us) + hybrid sincos: half the 64 sincos
// per thread-step go through OCML __sincosf (VALU poly pipe), half through
// v_sin/v_cos (transcendental pipe). The two pipes execute concurrently;
// R9 used only VALU (2550 busy cyc/wave-step), R10 only trans. Trans pair
// issues FIRST so its ~16cyc/op execution hides under the OCML poly issue.
//
// Weights staged once in LDS; A-frags persistent in registers; activations
// pure-register; barrier-free loop; __launch_bounds__(256,2) (R8 lesson:
// tighter bounds re-trigger catastrophic scratch spill on the unified
// VGPR/AGPR file). Wave owns 16 samples; lane (c=l&15, g=l>>4). B-frag
// (kt,qq,r) holds neuron n = 32kt+16qq+4g+r; C layout row = 16mt+4g+r makes
// lane g's C-quads exactly its next-layer B-frags (HW-verified R5-R13).
// ---------------------------------------------------------------------------
extern "C" __global__ void __launch_bounds__(256, 2)
fbsnn_kernel(const float* __restrict__ W0, const float* __restrict__ b0,
             const float* __restrict__ W1, const float* __restrict__ b1,
             const float* __restrict__ W2, const float* __restrict__ b2,
             const float* __restrict__ W3, const float* __restrict__ b3,
             const float* __restrict__ W4, const float* __restrict__ b4,
             const float* __restrict__ y0p, const float* __restrict__ dW,
             float* __restrict__ slots)
{
    __shared__ unsigned ldsA[6144];    // A-frags, u32-packed f16 pairs (24.5 KB)
    __shared__ float    ldsWA[64];     // L0 t-weights, pairs per (g,qi,h)
    __shared__ float    ldsWB[64];     // L0 y-weights
    __shared__ float    ldsB0[64];     // L0 bias
    __shared__ float    ldsBias[192];  // [li][mt][g][r]
    __shared__ float    ldsW4[64];     // [mt][g][r]

    const int tid = threadIdx.x;
    const int l   = tid & 63;
    const int wu  = tid >> 6;
    const int c   = l & 15;
    const int g   = l >> 4;
    const int sample = blockIdx.x * 64 + wu * 16 + c;

    const float DT = 0.01f, SQDT = 0.1f;

    // ================= prep: stage weights into LDS =================
    {
        for (int idx = tid; idx < 6144; idx += 256) {
            int w   = idx & 3;
            int lam = (idx >> 2) & 63;
            int f   = (idx >> 8) & 7;
            int li  = idx >> 11;
            const float* Wsl = (li == 0) ? W1 : (li == 1) ? W2 : W3;
            int cc = lam & 15, gg = lam >> 4;
            int mt = f >> 1, kt = f & 1;
            int m = 16 * mt + cc;
            int k = 32 * kt + 16 * (w >> 1) + 4 * gg + ((2 * w) & 3);
            const float* Wp = Wsl + m * 64 + k;
            ldsA[(8 * li + f) * 256 + lam * 4 + w] = pkh2(Wp[0], Wp[1]);
        }
        if (tid < 32) {
            int gg = tid >> 3, qi = (tid >> 1) & 3, h = tid & 1;
            int n0 = 32 * (qi >> 1) + 16 * (qi & 1) + 4 * gg + 2 * h;
            ldsWA[2 * tid]     = W0[2 * n0];
            ldsWA[2 * tid + 1] = W0[2 * n0 + 2];
            ldsWB[2 * tid]     = W0[2 * n0 + 1];
            ldsWB[2 * tid + 1] = W0[2 * n0 + 3];
            ldsB0[2 * tid]     = b0[n0];
            ldsB0[2 * tid + 1] = b0[n0 + 1];
        }
        if (tid < 192) {
            int li = tid >> 6, mt = (tid >> 4) & 3, gg = (tid >> 2) & 3, r = tid & 3;
            ldsBias[tid] = ((li == 0) ? b1 : (li == 1) ? b2 : b3)[16 * mt + 4 * gg + r];
        }
        if (tid < 64) {
            int mt = tid >> 4, gg = (tid >> 2) & 3, r = tid & 3;
            ldsW4[tid] = W4[16 * mt + 4 * gg + r];
        }
    }
    __syncthreads();   // only barrier; LDS is read-only below

    // ---- persistent A-fragments: load once, keep in registers (96 regs) ----
    half8 AF[3][4][2];
    #pragma unroll
    for (int li = 0; li < 3; ++li)
        #pragma unroll
        for (int mt = 0; mt < 4; ++mt)
            #pragma unroll
            for (int kt = 0; kt < 2; ++kt)
                AF[li][mt][kt] =
                    *(const half8*)&ldsA[(8 * li + 2 * mt + kt) * 256 + l * 4];

    // ---- W4 per-lane quads ----
    f32x4 W4l[4];
    #pragma unroll
    for (int mt = 0; mt < 4; ++mt)
        W4l[mt] = *(const f32x4*)&ldsW4[(mt * 4 + g) * 4];

    const float b4v = b4[0];
    float y = y0p[0];
    float t = 0.0f;
    float Y0 = 0.f, dY0 = 0.f, q0 = 0.f, Z0 = 0.f, dws = 0.f, loss = 0.f;

    #pragma unroll 1
    for (int s = 0; s <= NSTEPS; ++s) {
        float dwv = 0.0f;
        if (s < NSTEPS) dwv = dW[s * BATCH + sample];   // prefetch early

        // ============ layer 0: build B-frags in registers ============
        // h=1 pair -> trans pipe (issued first), h=0 pair -> OCML poly.
        half8 BX[2], BV[2];
        #pragma unroll
        for (int kt = 0; kt < 2; ++kt) {
            u32x4 ux, uv;
            #pragma unroll
            for (int qq = 0; qq < 2; ++qq) {
                int qi = 2 * kt + qq;
                int o0 = g * 8 + qi * 2;         // h = 0
                int o1 = o0 + 1;                 // h = 1
                f32x2 wa1 = *(const f32x2*)&ldsWA[2 * o1];
                f32x2 wb1 = *(const f32x2*)&ldsWB[2 * o1];
                f32x2 bb1 = *(const f32x2*)&ldsB0[2 * o1];
                float z2 = fmaf(wa1[0], t, fmaf(wb1[0], y, bb1[0]));
                float z3 = fmaf(wa1[1], t, fmaf(wb1[1], y, bb1[1]));
                float s2, c2, s3, c3;
                tsincos(z2, s2, c2);             // trans pipe, issue first
                tsincos(z3, s3, c3);
                f32x2 wa0 = *(const f32x2*)&ldsWA[2 * o0];
                f32x2 wb0 = *(const f32x2*)&ldsWB[2 * o0];
                f32x2 bb0 = *(const f32x2*)&ldsB0[2 * o0];
                float z0 = fmaf(wa0[0], t, fmaf(wb0[0], y, bb0[0]));
                float z1 = fmaf(wa0[1], t, fmaf(wb0[1], y, bb0[1]));
                float s0, c0, s1, c1;
                __sincosf(z0, &s0, &c0);         // VALU poly, overlaps trans
                __sincosf(z1, &s1, &c1);
                ux[2 * qq + 0] = pkh2(s0, s1);
                ux[2 * qq + 1] = pkh2(s2, s3);
                uv[2 * qq + 0] = pkh2(c0 * wb0[0], c1 * wb0[1]);
                uv[2 * qq + 1] = pkh2(c2 * wb1[0], c3 * wb1[1]);
            }
            BX[kt] = __builtin_bit_cast(half8, ux);
            BV[kt] = __builtin_bit_cast(half8, uv);
        }

        // ============ hidden layers 1..3 ============
        float Y1 = 0.f, dY1 = 0.f;
        #pragma unroll
        for (int li = 0; li < 3; ++li) {
            f32x4 ax[4], av[4];
            #pragma unroll
            for (int mt = 0; mt < 4; ++mt) {
                f32x4 ci = *(const f32x4*)&ldsBias[((li * 4 + mt) * 4 + g) * 4];
                f32x4 a = __builtin_amdgcn_mfma_f32_16x16x32_f16(AF[li][mt][0], BX[0], ci, 0, 0, 0);
                a = __builtin_amdgcn_mfma_f32_16x16x32_f16(AF[li][mt][1], BX[1], a, 0, 0, 0);
                ax[mt] = a;
                f32x4 v = {0.f, 0.f, 0.f, 0.f};
                v = __builtin_amdgcn_mfma_f32_16x16x32_f16(AF[li][mt][0], BV[0], v, 0, 0, 0);
                v = __builtin_amdgcn_mfma_f32_16x16x32_f16(AF[li][mt][1], BV[1], v, 0, 0, 0);
                av[mt] = v;
            }
            if (li < 2) {
                u32x4 nx[2], nv[2];
                #pragma unroll
                for (int mt = 0; mt < 4; ++mt) {
                    float s2, c2, s3, c3;
                    tsincos(ax[mt][2], s2, c2);  // trans pipe, issue first
                    tsincos(ax[mt][3], s3, c3);
                    float s0, c0, s1, c1;
                    __sincosf(ax[mt][0], &s0, &c0);  // VALU poly overlaps
                    __sincosf(ax[mt][1], &s1, &c1);
                    nx[mt >> 1][2 * (mt & 1) + 0] = pkh2(s0, s1);
                    nx[mt >> 1][2 * (mt & 1) + 1] = pkh2(s2, s3);
                    nv[mt >> 1][2 * (mt & 1) + 0] = pkh2(c0 * av[mt][0], c1 * av[mt][1]);
                    nv[mt >> 1][2 * (mt & 1) + 1] = pkh2(c2 * av[mt][2], c3 * av[mt][3]);
                }
                BX[0] = __builtin_bit_cast(half8, nx[0]);
                BX[1] = __builtin_bit_cast(half8, nx[1]);
                BV[0] = __builtin_bit_cast(half8, nv[0]);
                BV[1] = __builtin_bit_cast(half8, nv[1]);
            } else {
                float sx = 0.f, sv = 0.f;
                #pragma unroll
                for (int mt = 0; mt < 4; ++mt) {
                    float s2, c2, s3, c3;
                    tsincos(ax[mt][2], s2, c2);  // trans first
                    tsincos(ax[mt][3], s3, c3);
                    float s0, c0, s1, c1;
                    __sincosf(ax[mt][0], &s0, &c0);
                    __sincosf(ax[mt][1], &s1, &c1);
                    sx = fmaf(W4l[mt][0], s0, sx);
                    sx = fmaf(W4l[mt][1], s1, sx);
                    sx = fmaf(W4l[mt][2], s2, sx);
                    sx = fmaf(W4l[mt][3], s3, sx);
                    sv = fmaf(W4l[mt][0], c0 * av[mt][0], sv);
                    sv = fmaf(W4l[mt][1], c1 * av[mt][1], sv);
                    sv = fmaf(W4l[mt][2], c2 * av[mt][2], sv);
                    sv = fmaf(W4l[mt][3], c3 * av[mt][3], sv);
                }
                sx += __shfl_xor(sx, 16); sx += __shfl_xor(sx, 32);
                sv += __shfl_xor(sv, 16); sv += __shfl_xor(sv, 32);
                Y1  = sx + b4v;
                dY1 = sv;
            }
        }

        // ============ trajectory / loss ============
        if (s > 0) {
            float Yt = Y0 - q0 * q0 * DT + Z0 * dws;
            float d  = Y1 - Yt;
            loss += d * d;
        }
        Y0 = Y1; dY0 = dY1;
        if (s < NSTEPS) {
            Z0  = 0.5f * dY0;
            q0  = -dY0;                 // exact (power-of-2 constants)
            dws = dwv * SQDT;
            y   = y + q0 * DT + 0.5f * dws;
            t   = t + DT;
        }
    }

    // terminal: (YN - yN^2)^2 + (dYN - 2*yN)^2
    float d1 = Y0 - y * y;
    float d2 = dY0 - 2.0f * y;
    loss += d1 * d1 + d2 * d2;

    // 4 g-lanes share a sample -> mask, then wave butterfly
    float lv = (g == 0) ? loss : 0.0f;
    #pragma unroll
    for (int off = 1; off < 64; off <<= 1)
        lv += __shfl_xor(lv, off);
    if (l == 0)
        atomicAdd(&slots[(blockIdx.x * 4 + wu) & 255], lv);
}

extern "C" __global__ void finish_kernel(const float* __restrict__ slots,
                                         float* __restrict__ out) {
    int l = threadIdx.x;   // 64 threads
    float v = slots[l] + slots[64 + l] + slots[128 + l] + slots[192 + l];
    #pragma unroll
    for (int off = 1; off < 64; off <<= 1)
        v += __shfl_xor(v, off);
    if (l == 0) out[0] = v * (1.0f / (float)BATCH);
}

extern "C" void kernel_launch(void* const* d_in, const int* in_sizes, int n_in,
                              void* d_out, int out_size, void* d_ws, size_t ws_size,
                              hipStream_t stream) {
    const float* W0  = (const float*)d_in[0];
    const float* b0  = (const float*)d_in[1];
    const float* W1  = (const float*)d_in[2];
    const float* b1  = (const float*)d_in[3];
    const float* W2  = (const float*)d_in[4];
    const float* b2  = (const float*)d_in[5];
    const float* W3  = (const float*)d_in[6];
    const float* b3  = (const float*)d_in[7];
    const float* W4  = (const float*)d_in[8];
    const float* b4  = (const float*)d_in[9];
    const float* y0p = (const float*)d_in[10];
    const float* dW  = (const float*)d_in[11];
    float* slots = (float*)d_ws;

    (void)hipMemsetAsync(d_ws, 0, 256 * sizeof(float), stream);

    dim3 grid(BATCH / 64);   // 2048 blocks x 4 independent waves (16 samples)
    dim3 block(256);
    fbsnn_kernel<<<grid, block, 0, stream>>>(W0, b0, W1, b1, W2, b2, W3, b3,
                                             W4, b4, y0p, dW, slots);
    finish_kernel<<<1, 64, 0, stream>>>(slots, (float*)d_out);
}